// Round 2
// baseline (4993.303 us; speedup 1.0000x reference)
//
#include <hip/hip_runtime.h>
#include <stdint.h>

// ================= problem constants =================
#define B_SZ   128
#define T_LEN  2048
#define DIN    256
#define NU     512
#define NOUT   64
#define EPS_F  0.01f
#define GAM_F  0.01f
#define KT     32
#define NTILES (T_LEN / KT)

typedef uint32_t u32;
typedef _Float16 h16;
typedef _Float16 __attribute__((ext_vector_type(2))) h16x2;
typedef _Float16 __attribute__((ext_vector_type(8))) h16x8;
typedef float    __attribute__((ext_vector_type(4))) f32x4;
typedef unsigned int __attribute__((ext_vector_type(4))) u32x4;   // asm-friendly 4-VGPR tuple

// ws layout (u32 units):
//   WS_A    : 131072 u32 (512KB)  A = W - W^T - gamma*I, packed f16x2, scan layout
//   WS_WH   : 65536 u32  (256KB)  Vh_w as f16 [512][256]
//   WS_WZ   : 65536 u32  (256KB)  Vz_w as f16 [512][256]
//   WS_EXCH : 128*2*2*43 uint4    stamped h-half exchange quads {stamp,3 pairs}
#define WS_A    0
#define WS_WH   131072
#define WS_WZ   196608
#define WS_EXCH 262144
#define NQUAD   43

__device__ __forceinline__ u32 pack2(float lo, float hi) {
  h16x2 v; v.x = (h16)lo; v.y = (h16)hi;
  return __builtin_bit_cast(u32, v);
}

__device__ __forceinline__ float fdot2(u32 h2, u32 a2, float acc) {
#if __has_builtin(__builtin_amdgcn_fdot2)
  return __builtin_amdgcn_fdot2(__builtin_bit_cast(h16x2, h2),
                                __builtin_bit_cast(h16x2, a2), acc, false);
#else
  h16x2 hh = __builtin_bit_cast(h16x2, h2);
  h16x2 aa = __builtin_bit_cast(h16x2, a2);
  return acc + (float)hh.x * (float)aa.x + (float)hh.y * (float)aa.y;
#endif
}

// ================= prep: pack A + weights to f16, zero exch/out =================
__global__ void antirnn_prep(const float* __restrict__ Vh_w,
                             const float* __restrict__ Vz_w,
                             const float* __restrict__ W,
                             u32* __restrict__ ws,
                             float* __restrict__ out) {
  const int idx = blockIdx.x * blockDim.x + threadIdx.x;
  const int stride = gridDim.x * blockDim.x;

  // A pack: decode flat u32 index -> (jh,w,c4,pq,l,e); pair of rows i0,i0+1 at col j
  for (int u = idx; u < 131072; u += stride) {
    int e  = u & 3;
    int l  = (u >> 2) & 63;
    int pq = (u >> 8) & 15;
    int c4 = (u >> 12) & 3;
    int w  = (u >> 14) & 3;
    int jh = (u >> 16) & 1;
    int p  = pq * 4 + e;
    int i0 = w * 128 + 2 * p;
    int j  = jh * 256 + l * 4 + c4;
    float lo = W[i0 * NU + j]       - W[j * NU + i0]     - (i0 == j     ? GAM_F : 0.f);
    float hi = W[(i0 + 1) * NU + j] - W[j * NU + i0 + 1] - ((i0 + 1) == j ? GAM_F : 0.f);
    ws[WS_A + u] = pack2(lo, hi);
  }
  // weight conversion (row-major [512][256] f16, pairs along k)
  for (int u = idx; u < 65536; u += stride) {
    int fl = u * 2;
    ws[WS_WH + u] = pack2(Vh_w[fl], Vh_w[fl + 1]);
    ws[WS_WZ + u] = pack2(Vz_w[fl], Vz_w[fl + 1]);
  }
  // zero exchange quads (stamps must be 0 != any step) and output (atomicAdd target)
  for (int u = idx; u < B_SZ * 2 * 2 * NQUAD * 4; u += stride) ws[WS_EXCH + u] = 0;
  for (int u = idx; u < B_SZ * NOUT; u += stride) out[u] = 0.f;
}

// ================= scan: 256 WGs x 256 thr; pair (g, g+128) splits A columns =================
__global__ __launch_bounds__(256, 1) void antirnn_scan(
    const float* __restrict__ x,
    const float* __restrict__ vh_b, const float* __restrict__ vz_b,
    const float* __restrict__ fc_w, const float* __restrict__ fc_b,
    u32* __restrict__ ws, float* __restrict__ out) {

  __shared__ h16  xs[32 * 256];      // 16KB x-tile (f16, xor-swizzled rows)
  __shared__ h16  ph[256 * 36];      // 18KB vh proj tile [n_local][36]
  __shared__ h16  pz[256 * 36];      // 18KB vz proj tile
  __shared__ float part[4 * 256];    // 4KB  per-wave partial sums [w][col_local]
  __shared__ u32  hp[256];           // 1KB  full h as f16x2 pairs (global pair index)

  const int tid = threadIdx.x;
  const int w   = tid >> 6;          // wave id = i-block (128 i's each)
  const int l   = tid & 63;
  const int bid = blockIdx.x;
  const int b   = bid & 127;         // chain = batch
  const int jh  = bid >> 7;          // column half owned: j in [jh*256, jh*256+256)

  // ---- load my A column-slice into registers: 4 cols x 64 i-pairs per lane ----
  u32 a[256];
  {
    const uint4* Ap = reinterpret_cast<const uint4*>(ws + WS_A) + (jh * 4 + w) * 4096 + l;
#pragma unroll
    for (int rq = 0; rq < 64; ++rq) {
      uint4 q = Ap[rq * 64];
      int base = (rq >> 4) * 64 + (rq & 15) * 4;
      a[base + 0] = q.x; a[base + 1] = q.y; a[base + 2] = q.z; a[base + 3] = q.w;
    }
  }

  hp[tid] = 0;  // h(0) = 0

  const float* xrow = x + (long)b * T_LEN * DIN;
  float hreg = 0.f;                               // this lane owns local col c = tid
  const h16* Wn_h = reinterpret_cast<const h16*>(ws + WS_WH);
  const h16* Wn_z = reinterpret_cast<const h16*>(ws + WS_WZ);
  uint4* exch = reinterpret_cast<uint4*>(ws + WS_EXCH);

  const int  peerHalf   = 1 - jh;
  const bool isPeerWave = ((w >> 1) == peerHalf); // these 2 waves consume the peer's h-half
  const int  qbase      = (w & 1) * 21;           // quad ranges 0..21 / 21..42 (q21 overlap ok)

#pragma unroll 1
  for (int tile = 0; tile < NTILES; ++tile) {
    // ---- stage x tile: f32 -> f16, row-xor-swizzled ----
#pragma unroll
    for (int it = 0; it < 16; ++it) {
      int fp = it * 256 + tid;                    // pair index in [0,4096)
      int s  = fp >> 7, dp = fp & 127;
      float2 v = *reinterpret_cast<const float2*>(xrow + (tile * KT + s) * DIN + dp * 2);
      int byteaddr = (s * 512 + dp * 4) ^ ((s & 7) << 4);
      *reinterpret_cast<u32*>(reinterpret_cast<char*>(xs) + byteaddr) = pack2(v.x, v.y);
    }
    __syncthreads();

    // ---- proj MFMA: [32 steps x 256 own cols]; wave -> n-block w*64 ----
    {
      f32x4 acch[2][4], accz[2][4];
#pragma unroll
      for (int mt = 0; mt < 2; ++mt)
#pragma unroll
        for (int nt = 0; nt < 4; ++nt) {
          acch[mt][nt] = (f32x4){0.f, 0.f, 0.f, 0.f};
          accz[mt][nt] = (f32x4){0.f, 0.f, 0.f, 0.f};
        }
      const int lk = (l >> 4) * 8;
      const int ln = l & 15;
#pragma unroll
      for (int kk = 0; kk < 8; ++kk) {
        h16x8 af[2];
#pragma unroll
        for (int mt = 0; mt < 2; ++mt) {
          int s = mt * 16 + ln;
          int byteaddr = (s * 512 + kk * 64 + (l >> 4) * 16) ^ ((s & 7) << 4);
          af[mt] = *reinterpret_cast<const h16x8*>(reinterpret_cast<const char*>(xs) + byteaddr);
        }
#pragma unroll
        for (int nt = 0; nt < 4; ++nt) {
          int ng = jh * 256 + w * 64 + nt * 16 + ln;   // global unit row
          h16x8 bh = *reinterpret_cast<const h16x8*>(Wn_h + ng * 256 + kk * 32 + lk);
          h16x8 bz = *reinterpret_cast<const h16x8*>(Wn_z + ng * 256 + kk * 32 + lk);
#pragma unroll
          for (int mt = 0; mt < 2; ++mt) {
            acch[mt][nt] = __builtin_amdgcn_mfma_f32_16x16x32_f16(af[mt], bh, acch[mt][nt], 0, 0, 0);
            accz[mt][nt] = __builtin_amdgcn_mfma_f32_16x16x32_f16(af[mt], bz, accz[mt][nt], 0, 0, 0);
          }
        }
      }
      // write proj tiles: D layout col=lane&15, row=(lane>>4)*4+reg
#pragma unroll
      for (int nt = 0; nt < 4; ++nt) {
        int n  = w * 64 + nt * 16 + ln;                // local col
        float bh_ = vh_b[jh * 256 + n];
        float bz_ = vz_b[jh * 256 + n];
#pragma unroll
        for (int mt = 0; mt < 2; ++mt) {
          int s0 = mt * 16 + (l >> 4) * 4;
          *reinterpret_cast<u32*>(&ph[n * 36 + s0])     = pack2(acch[mt][nt].x + bh_, acch[mt][nt].y + bh_);
          *reinterpret_cast<u32*>(&ph[n * 36 + s0 + 2]) = pack2(acch[mt][nt].z + bh_, acch[mt][nt].w + bh_);
          *reinterpret_cast<u32*>(&pz[n * 36 + s0])     = pack2(accz[mt][nt].x + bz_, accz[mt][nt].y + bz_);
          *reinterpret_cast<u32*>(&pz[n * 36 + s0 + 2]) = pack2(accz[mt][nt].z + bz_, accz[mt][nt].w + bz_);
        }
      }
    }
    __syncthreads();

    // ---- 32 sequential steps ----
#pragma unroll 1
    for (int s = 0; s < KT; ++s) {
      const int t = tile * KT + s;

      // receive peer h-half: stamped quads, parity t&1 (one coherent load = poll+data)
      if (isPeerWave && t > 0 && l <= 21) {
        int q = qbase + l;                               // 0..42
        const uint4* src = exch + (((b * 2 + peerHalf) * 2 + (t & 1)) * NQUAD) + q;
        u32x4 v;
        do {
          asm volatile("global_load_dwordx4 %0, %1, off sc0 sc1\n\ts_waitcnt vmcnt(0)"
                       : "=v"(v) : "v"(src) : "memory");
        } while (v[0] != (u32)t);
#pragma unroll
        for (int k2 = 0; k2 < 3; ++k2) {
          int pi = q * 3 + k2;
          if (pi < 128) hp[peerHalf * 128 + pi] = v[1 + k2];
        }
      }

      // stage my wave's 64 h-pairs (broadcast ds_read_b128) and dot: 4 cols x 128 i
      u32 hq[64];
      {
        const uint4* hpw = reinterpret_cast<const uint4*>(&hp[w * 64]);
#pragma unroll
        for (int pq = 0; pq < 16; ++pq) {
          uint4 qq = hpw[pq];
          hq[pq * 4 + 0] = qq.x; hq[pq * 4 + 1] = qq.y;
          hq[pq * 4 + 2] = qq.z; hq[pq * 4 + 3] = qq.w;
        }
      }
      float acc0 = 0.f, acc1 = 0.f, acc2 = 0.f, acc3 = 0.f;
#pragma unroll
      for (int p = 0; p < 64; ++p) {
        acc0 = fdot2(hq[p], a[p],        acc0);
        acc1 = fdot2(hq[p], a[64 + p],   acc1);
        acc2 = fdot2(hq[p], a[128 + p],  acc2);
        acc3 = fdot2(hq[p], a[192 + p],  acc3);
      }
      {
        f32x4 pv = {acc0, acc1, acc2, acc3};
        *reinterpret_cast<f32x4*>(&part[w * 256 + l * 4]) = pv;
      }
      __syncthreads();

      // epilogue: every lane owns local col c = tid
      {
        float pre = part[tid] + part[256 + tid] + part[512 + tid] + part[768 + tid];
        float uh  = pre + (float)ph[tid * 36 + s];
        float uz  = pre + (float)pz[tid * 36 + s];
        float uhc = fminf(fmaxf(uh, -20.f), 20.f);
        float e2  = __expf(2.f * uhc);
        float th  = 1.f - 2.f / (e2 + 1.f);
        float sg  = 1.f / (1.f + __expf(-uz));
        hreg += EPS_F * th * sg;
        float other = __shfl_xor(hreg, 1, 64);
        if (!(tid & 1)) hp[jh * 128 + (tid >> 1)] = pack2(hreg, other);
      }
      __syncthreads();

      // send my h-half (stamp t+1, parity (t+1)&1); fire-and-forget, quad is self-flagging
      if ((t + 1 < T_LEN) && w == 0 && l < NQUAD) {
        int p0 = l * 3;
        u32 v0 = hp[jh * 128 + p0];
        u32 v1 = (p0 + 1 < 128) ? hp[jh * 128 + p0 + 1] : 0u;
        u32 v2 = (p0 + 2 < 128) ? hp[jh * 128 + p0 + 2] : 0u;
        u32x4 qd; qd[0] = (u32)(t + 1); qd[1] = v0; qd[2] = v1; qd[3] = v2;
        uint4* dst = exch + (((b * 2 + jh) * 2 + ((t + 1) & 1)) * NQUAD) + l;
        asm volatile("global_store_dwordx4 %0, %1, off sc0 sc1"
                     :: "v"(dst), "v"(qd) : "memory");
      }
    }
  }

  // ---- final fc: out[b,o] += sum_c h(c) * fc_w[o, jh*256+c] ----
  __syncthreads();
  part[tid] = hreg;
  __syncthreads();
  if (tid < NOUT) {
    float acc = (jh == 0) ? fc_b[tid] : 0.f;
    const float* fr = fc_w + tid * NU + jh * 256;
#pragma unroll 4
    for (int c = 0; c < 256; ++c) acc += part[c] * fr[c];
    atomicAdd(out + b * NOUT + tid, acc);
  }
}

// ================= launcher =================
extern "C" void kernel_launch(void* const* d_in, const int* in_sizes, int n_in,
                              void* d_out, int out_size, void* d_ws, size_t ws_size,
                              hipStream_t stream) {
  const float* x    = (const float*)d_in[0];
  const float* Vh_w = (const float*)d_in[1];
  const float* Vh_b = (const float*)d_in[2];
  const float* Vz_w = (const float*)d_in[3];
  const float* Vz_b = (const float*)d_in[4];
  const float* W    = (const float*)d_in[5];
  const float* fc_w = (const float*)d_in[6];
  const float* fc_b = (const float*)d_in[7];
  float* out = (float*)d_out;
  u32*   ws  = (u32*)d_ws;

  // prep: pack A/weights into ws, zero exchange stamps + output (runs every launch)
  antirnn_prep<<<512, 256, 0, stream>>>(Vh_w, Vz_w, W, ws, out);
  // scan: 256 persistent WGs (one per CU), pairs (g, g+128) per chain
  antirnn_scan<<<256, 256, 0, stream>>>(x, Vh_b, Vz_b, fc_w, fc_b, ws, out);
}